// Round 13
// baseline (294.799 us; speedup 1.0000x reference)
//
#include <hip/hip_runtime.h>

// Problem constants: B=512, L=128, N=64, H=16, PW=30, FEAT=480
#define LSX 65    // xs row stride (64+1)
#define FCS 40    // fcmm LDS row stride (32+8 ushorts)

typedef __bf16 bf16x8 __attribute__((ext_vector_type(8)));
typedef float  f32x4  __attribute__((ext_vector_type(4)));

__device__ __forceinline__ unsigned short f2bf_rne(float x) {
    unsigned int u = __float_as_uint(x);
    unsigned int r = u + 0x7FFFu + ((u >> 16) & 1u);
    return (unsigned short)(r >> 16);
}

// quad_perm broadcast of quad-lane Q (DPP ctrl = Q*0x55)
#define QB(x, C) __uint_as_float((unsigned)__builtin_amdgcn_update_dpp( \
        0, (int)__float_as_uint(x), (C), 0xF, 0xF, false))
#define RDLANE(x, L) __uint_as_float((unsigned)__builtin_amdgcn_readlane( \
        (int)__float_as_uint(x), (L)))

// ---------------------------------------------------------------------------
// Kernel 0: Wih0 [64,480] -> MFMA B-fragment layout, bf16 hi/lo
// ---------------------------------------------------------------------------
__global__ __launch_bounds__(256) void k_permW(const float* __restrict__ Wih0,
                                               unsigned short* __restrict__ Wfh,
                                               unsigned short* __restrict__ Wfl)
{
    int idx = blockIdx.x * 256 + threadIdx.x;     // < 30720
    int j = idx & 7, lane = (idx >> 3) & 63, nt = (idx >> 9) & 3, ch = idx >> 11;
    int g = nt * 16 + (lane & 15);
    int k = (lane >> 4) * 8 + j;
    int f = ch * 32 + k, q = f >> 4, h = f & 15;
    float v = Wih0[g * 480 + h * 30 + q];
    unsigned int uv = __float_as_uint(v);
    Wfh[idx] = (unsigned short)(uv >> 16);
    Wfl[idx] = f2bf_rne(v - __uint_as_float(uv & 0xFFFF0000u));
}

// ---------------------------------------------------------------------------
// Kernel 0b: generic fp32 -> bf16 hi/lo split (per float4)
// ---------------------------------------------------------------------------
__global__ __launch_bounds__(256) void k_cvt(const float* __restrict__ in,
                                             unsigned short* __restrict__ oh,
                                             unsigned short* __restrict__ ol,
                                             int n4)
{
    int i = blockIdx.x * 256 + threadIdx.x;
    if (i >= n4) return;
    float4 v = ((const float4*)in)[i];
    float vv[4] = {v.x, v.y, v.z, v.w};
    unsigned short hs[4], ls[4];
    #pragma unroll
    for (int e = 0; e < 4; ++e) {
        unsigned int u = __float_as_uint(vv[e]);
        hs[e] = (unsigned short)(u >> 16);
        ls[e] = f2bf_rne(vv[e] - __uint_as_float(u & 0xFFFF0000u));
    }
    uint2 ph = make_uint2((unsigned)hs[0] | ((unsigned)hs[1] << 16),
                          (unsigned)hs[2] | ((unsigned)hs[3] << 16));
    uint2 pl = make_uint2((unsigned)ls[0] | ((unsigned)ls[1] << 16),
                          (unsigned)ls[2] | ((unsigned)ls[3] << 16));
    *(uint2*)&oh[i * 4] = ph;
    *(uint2*)&ol[i * 4] = pl;
}

// ---------------------------------------------------------------------------
// Kernel 1: dual-axis attention + conv/bn/pool + MFMA GEMM. [round-12 verbatim]
// ---------------------------------------------------------------------------
__global__ __launch_bounds__(256, 4) void k_attn_conv(
    const float* __restrict__ x1, const float* __restrict__ x2,
    const float* __restrict__ w_x_q, const float* __restrict__ w_x_k,
    const float* __restrict__ w_y_q, const float* __restrict__ w_y_k,
    const float* __restrict__ pos_emb,
    const float* __restrict__ conv_w, const float* __restrict__ conv_b,
    const float* __restrict__ bn_g, const float* __restrict__ bn_b,
    const float* __restrict__ bn_m, const float* __restrict__ bn_v,
    const unsigned short* __restrict__ Wfh, const unsigned short* __restrict__ Wfl,
    float* __restrict__ pre0)
{
    __shared__ float xs[128 * LSX];
    __shared__ float xkp[2][64], ykv[128], uu[64], vv[128];
    __shared__ float sxs[128], sysp[2][64], sys[64];
    __shared__ float cw[16][4], cbs[16], bnsh[16];

    const int bg = blockIdx.x;
    const int t  = threadIdx.x;
    const float* x = (bg < 512 ? x1 : x2) + (size_t)(bg & 511) * 8192;

    #pragma unroll
    for (int r = 0; r < 32; ++r) {
        int pos = r * 256 + t;
        xs[(pos >> 6) * LSX + (pos & 63)] = x[pos];
    }
    if (t < 16) {
        float sc = bn_g[t] * rsqrtf(bn_v[t] + 1e-5f);   // > 0 for given inputs
        bnsh[t] = bn_b[t] - bn_m[t] * sc;
        cbs[t]  = conv_b[t] * sc;
        cw[t][0] = conv_w[t * 4 + 0] * sc; cw[t][1] = conv_w[t * 4 + 1] * sc;
        cw[t][2] = conv_w[t * 4 + 2] * sc; cw[t][3] = conv_w[t * 4 + 3] * sc;
    }
    __syncthreads();

    if (t < 128) {
        int n = t & 63, hf = t >> 6;
        const float* base = &xs[hf * 64 * LSX + n];
        const float* wk = w_x_k + hf * 64;
        float s0 = 0.f, s1 = 0.f, s2 = 0.f, s3 = 0.f;
        for (int l = 0; l < 64; l += 4) {
            s0 += base[(l + 0) * LSX] * wk[l + 0];
            s1 += base[(l + 1) * LSX] * wk[l + 1];
            s2 += base[(l + 2) * LSX] * wk[l + 2];
            s3 += base[(l + 3) * LSX] * wk[l + 3];
        }
        xkp[hf][n] = (s0 + s1) + (s2 + s3);
    } else {
        int l = t - 128;
        const float* row = &xs[l * LSX];
        float s0 = 0.f, s1 = 0.f, s2 = 0.f, s3 = 0.f;
        for (int n = 0; n < 64; n += 4) {
            s0 += w_y_k[n + 0] * row[n + 0];
            s1 += w_y_k[n + 1] * row[n + 1];
            s2 += w_y_k[n + 2] * row[n + 2];
            s3 += w_y_k[n + 3] * row[n + 3];
        }
        ykv[l] = (s0 + s1) + (s2 + s3);
    }
    __syncthreads();

    if (t < 64) {
        const float* wq = w_x_q + t * 64;
        float s0 = 0.f, s1 = 0.f, s2 = 0.f, s3 = 0.f;
        for (int n = 0; n < 64; n += 4) {
            s0 += wq[n + 0] * (xkp[0][n + 0] + xkp[1][n + 0]);
            s1 += wq[n + 1] * (xkp[0][n + 1] + xkp[1][n + 1]);
            s2 += wq[n + 2] * (xkp[0][n + 2] + xkp[1][n + 2]);
            s3 += wq[n + 3] * (xkp[0][n + 3] + xkp[1][n + 3]);
        }
        uu[t] = (s0 + s1) + (s2 + s3);
    } else if (t < 192) {
        int m = t - 64;
        float s0 = 0.f, s1 = 0.f, s2 = 0.f, s3 = 0.f;
        for (int l = 0; l < 128; l += 4) {
            s0 += ykv[l + 0] * w_y_q[(l + 0) * 128 + m];
            s1 += ykv[l + 1] * w_y_q[(l + 1) * 128 + m];
            s2 += ykv[l + 2] * w_y_q[(l + 2) * 128 + m];
            s3 += ykv[l + 3] * w_y_q[(l + 3) * 128 + m];
        }
        vv[m] = (s0 + s1) + (s2 + s3);
    }
    __syncthreads();

    if (t < 128) {
        const float* row = &xs[t * LSX];
        float s0 = 0.f, s1 = 0.f, s2 = 0.f, s3 = 0.f;
        for (int m = 0; m < 64; m += 4) {
            s0 += row[m + 0] * uu[m + 0];
            s1 += row[m + 1] * uu[m + 1];
            s2 += row[m + 2] * uu[m + 2];
            s3 += row[m + 3] * uu[m + 3];
        }
        sxs[t] = (s0 + s1) + (s2 + s3);
    } else {
        int n = (t - 128) & 63, hf = (t - 128) >> 6;
        const float* base = &xs[hf * 64 * LSX + n];
        const float* vp = vv + hf * 64;
        float s0 = 0.f, s1 = 0.f, s2 = 0.f, s3 = 0.f;
        for (int m = 0; m < 64; m += 4) {
            s0 += vp[m + 0] * base[(m + 0) * LSX];
            s1 += vp[m + 1] * base[(m + 1) * LSX];
            s2 += vp[m + 2] * base[(m + 2) * LSX];
            s3 += vp[m + 3] * base[(m + 3) * LSX];
        }
        sysp[hf][n] = (s0 + s1) + (s2 + s3);
    }
    __syncthreads();

    if (t < 64) {
        float a = sxs[t], b = sxs[t + 64];
        float mx = fmaxf(a, b);
        #pragma unroll
        for (int d = 32; d > 0; d >>= 1) mx = fmaxf(mx, __shfl_xor(mx, d, 64));
        float e0 = __expf(a - mx), e1 = __expf(b - mx);
        float s = e0 + e1;
        #pragma unroll
        for (int d = 32; d > 0; d >>= 1) s += __shfl_xor(s, d, 64);
        float r = 10.f / s;
        sxs[t] = e0 * r; sxs[t + 64] = e1 * r;
    } else if (t < 128) {
        int n = t - 64;
        float a = sysp[0][n] + sysp[1][n];
        float mx = a;
        #pragma unroll
        for (int d = 32; d > 0; d >>= 1) mx = fmaxf(mx, __shfl_xor(mx, d, 64));
        float e = __expf(a - mx);
        float s = e;
        #pragma unroll
        for (int d = 32; d > 0; d >>= 1) s += __shfl_xor(s, d, 64);
        sys[n] = e * (10.f / s);
    }
    __syncthreads();

    #pragma unroll
    for (int r = 0; r < 32; ++r) {
        int pos = r * 256 + t;
        int l = pos >> 6, n = pos & 63;
        xs[l * LSX + n] = xs[l * LSX + n] * sxs[l] * sys[n] + pos_emb[pos];
    }
    __syncthreads();

    const int lane = t & 63, w = t >> 6;
    const int m16 = lane & 15, kq = lane >> 4;
    const int hb = (kq & 1) * 8;
    const int qoff = kq >> 1;

    float cwr0[8], cwr1[8], cwr2[8], cwr3[8], cbr[8], bhr[8];
    #pragma unroll
    for (int j = 0; j < 8; ++j) {
        cwr0[j] = cw[hb + j][0]; cwr1[j] = cw[hb + j][1];
        cwr2[j] = cw[hb + j][2]; cwr3[j] = cw[hb + j][3];
        cbr[j] = cbs[hb + j]; bhr[j] = bnsh[hb + j];
    }

    f32x4 acc[2][4];
    #pragma unroll
    for (int mt = 0; mt < 2; ++mt)
        #pragma unroll
        for (int nt = 0; nt < 4; ++nt) {
            f32x4 z = {0.f, 0.f, 0.f, 0.f};
            acc[mt][nt] = z;
        }

    for (int ch = 0; ch < 15; ++ch) {
        bf16x8 ah[2], al[2];
        const int q2 = 2 * (2 * ch + qoff);
        #pragma unroll
        for (int mt = 0; mt < 2; ++mt) {
            int row = w * 32 + mt * 16 + m16;
            const float* xr = &xs[row * LSX + q2];
            float o0 = xr[0], o1 = xr[1], o2 = xr[2], o3 = xr[3], o4 = xr[4];
            union { unsigned short us[8]; bf16x8 bv; } vh, vl;
            #pragma unroll
            for (int j = 0; j < 8; ++j) {
                float a = fmaf(o0, cwr0[j], fmaf(o1, cwr1[j], fmaf(o2, cwr2[j], fmaf(o3, cwr3[j], cbr[j]))));
                float b = fmaf(o1, cwr0[j], fmaf(o2, cwr1[j], fmaf(o3, cwr2[j], fmaf(o4, cwr3[j], cbr[j]))));
                float v = fmaxf(fmaxf(a, 0.f), fmaxf(b, 0.f)) + bhr[j];
                unsigned int uv = __float_as_uint(v);
                vh.us[j] = (unsigned short)(uv >> 16);
                vl.us[j] = f2bf_rne(v - __uint_as_float(uv & 0xFFFF0000u));
            }
            ah[mt] = vh.bv; al[mt] = vl.bv;
        }
        #pragma unroll
        for (int nh = 0; nh < 2; ++nh) {
            bf16x8 bh[2], bl[2];
            #pragma unroll
            for (int ni = 0; ni < 2; ++ni) {
                int o = ((ch * 4 + nh * 2 + ni) * 64 + lane) * 8;
                bh[ni] = *(const bf16x8*)&Wfh[o];
                bl[ni] = *(const bf16x8*)&Wfl[o];
            }
            #pragma unroll
            for (int mt = 0; mt < 2; ++mt)
                #pragma unroll
                for (int ni = 0; ni < 2; ++ni) {
                    int nt = nh * 2 + ni;
                    acc[mt][nt] = __builtin_amdgcn_mfma_f32_16x16x32_bf16(ah[mt], bh[ni], acc[mt][nt], 0, 0, 0);
                    acc[mt][nt] = __builtin_amdgcn_mfma_f32_16x16x32_bf16(al[mt], bh[ni], acc[mt][nt], 0, 0, 0);
                    acc[mt][nt] = __builtin_amdgcn_mfma_f32_16x16x32_bf16(ah[mt], bl[ni], acc[mt][nt], 0, 0, 0);
                }
        }
    }

    #pragma unroll
    for (int mt = 0; mt < 2; ++mt)
        #pragma unroll
        for (int nt = 0; nt < 4; ++nt)
            #pragma unroll
            for (int r = 0; r < 4; ++r) {
                int row = w * 32 + mt * 16 + (lane >> 4) * 4 + r;
                int col = nt * 16 + m16;
                pre0[(size_t)bg * 8192 + row * 64 + col] = acc[mt][nt][r];
            }
}

// ---------------------------------------------------------------------------
// Kernel 2: producer-consumer LSTM, 4 sequences per block (8 waves, 512 thr).
// Wave wv<4: producer of local seq wv; wv>=4: consumer of local seq wv-4.
// Round-robin wave->SIMD puts P_k and C_k on SIMD k: 2 waves/SIMD fill each
// other's dependency stalls. Step math identical to round 12.
// ---------------------------------------------------------------------------
__global__ __launch_bounds__(512) void k_lstm(
    const float* __restrict__ pre0,
    const float* __restrict__ Whh0,
    const float* __restrict__ Wih1, const float* __restrict__ Whh1,
    const float* __restrict__ bih0, const float* __restrict__ bhh0,
    const float* __restrict__ bih1, const float* __restrict__ bhh1,
    unsigned short* __restrict__ fbh, unsigned short* __restrict__ fbl)
{
    __shared__ float zbuf[4][2][8][64];

    const int tid = threadIdx.x;
    const int lane = tid & 63;
    const int wv = tid >> 6;             // 0..7
    const bool isP = (wv < 4);
    const int sl = isP ? wv : wv - 4;    // local sequence 0..3
    const int seq = blockIdx.x * 4 + sl; // 0..255
    const int i = seq >> 7, j = seq & 127;
    const int a = lane & 3, u = lane >> 2;
    const int row = a * 16 + u;          // torch gate-row index
    const float pm = (a == 2) ? -2.f : -1.f;
    const float ka = (a == 2) ?  2.f :  1.f;
    const float kb = (a == 2) ? -1.f :  0.f;

    if (isP) {
        float w0[16], wi1[16];
        #pragma unroll
        for (int m = 0; m < 16; ++m) {
            w0[m]  = Whh0[row * 16 + m];
            wi1[m] = Wih1[row * 16 + m];
        }
        const float b0 = bih0[row] + bhh0[row];
        float h0[16];
        #pragma unroll
        for (int m = 0; m < 16; ++m) h0[m] = 0.f;
        float c0 = 0.f;

        const float* pp = pre0 + (size_t)i * 4194304 + (size_t)j * 64 + row;
        float pf[8];
        #pragma unroll
        for (int d = 0; d < 8; ++d) pf[d] = pp[(size_t)d * 8192];

#define STEP0(PRE, DD, BB)                                                      \
    {                                                                           \
        float sA = 0.f, sB = 0.f, sC = 0.f, sD = 0.f;                           \
        _Pragma("unroll")                                                       \
        for (int m = 0; m < 4; ++m) {                                           \
            sA += h0[m]      * w0[m];                                           \
            sB += h0[m + 4]  * w0[m + 4];                                       \
            sC += h0[m + 8]  * w0[m + 8];                                       \
            sD += h0[m + 12] * w0[m + 12];                                      \
        }                                                                       \
        float g0 = (PRE) + b0 + ((sA + sB) + (sC + sD));                        \
        float e0 = __expf(pm * g0);                                             \
        float v0 = fmaf(__builtin_amdgcn_rcpf(1.f + e0), ka, kb);               \
        float si = QB(v0, 0x00), sf = QB(v0, 0x55);                             \
        float tg = QB(v0, 0xAA), so = QB(v0, 0xFF);                             \
        c0 = fmaf(sf, c0, si * tg);                                             \
        float ec = __expf(-2.f * c0);                                           \
        float h0n = so * fmaf(2.f, __builtin_amdgcn_rcpf(1.f + ec), -1.f);      \
        float hn[16];                                                           \
        _Pragma("unroll")                                                       \
        for (int m = 0; m < 16; ++m) hn[m] = RDLANE(h0n, 4 * m);                \
        float zA = 0.f, zB = 0.f, zC = 0.f, zD = 0.f;                           \
        _Pragma("unroll")                                                       \
        for (int m = 0; m < 4; ++m) {                                           \
            zA += hn[m]      * wi1[m];                                          \
            zB += hn[m + 4]  * wi1[m + 4];                                      \
            zC += hn[m + 8]  * wi1[m + 8];                                      \
            zD += hn[m + 12] * wi1[m + 12];                                     \
        }                                                                       \
        zbuf[sl][BB][DD][lane] = (zA + zB) + (zC + zD);                         \
        _Pragma("unroll")                                                       \
        for (int m = 0; m < 16; ++m) h0[m] = hn[m];                             \
    }

        for (int tb = 0; tb < 64; ++tb) {
            const int bb = tb & 1;
            float nx[8];
            #pragma unroll
            for (int d = 0; d < 8; ++d)
                nx[d] = pp[(size_t)(tb * 8 + 8 + d) * 8192];
            STEP0(pf[0], 0, bb);
            STEP0(pf[1], 1, bb);
            STEP0(pf[2], 2, bb);
            STEP0(pf[3], 3, bb);
            STEP0(pf[4], 4, bb);
            STEP0(pf[5], 5, bb);
            STEP0(pf[6], 6, bb);
            STEP0(pf[7], 7, bb);
            #pragma unroll
            for (int d = 0; d < 8; ++d) pf[d] = nx[d];
            __syncthreads();
        }
        __syncthreads();   // pair with consumer's initial barrier
#undef STEP0
    } else {
        float wh1[16];
        #pragma unroll
        for (int m = 0; m < 16; ++m) wh1[m] = Whh1[row * 16 + m];
        const float b1 = bih1[row] + bhh1[row];
        float h1[16];
        #pragma unroll
        for (int m = 0; m < 16; ++m) h1[m] = 0.f;
        float c1 = 0.f;

        const size_t fbase = (size_t)i * 1048576 + (size_t)j * 16 + u;
        const bool st = (a == 0);

#define STEP1(ZZ, TT)                                                           \
    {                                                                           \
        float tA = 0.f, tB = 0.f, tC = 0.f, tD = 0.f;                           \
        _Pragma("unroll")                                                       \
        for (int m = 0; m < 4; ++m) {                                           \
            tA += h1[m]      * wh1[m];                                          \
            tB += h1[m + 4]  * wh1[m + 4];                                      \
            tC += h1[m + 8]  * wh1[m + 8];                                      \
            tD += h1[m + 12] * wh1[m + 12];                                     \
        }                                                                       \
        float g1 = (ZZ) + b1 + ((tA + tB) + (tC + tD));                         \
        float e1 = __expf(pm * g1);                                             \
        float v1 = fmaf(__builtin_amdgcn_rcpf(1.f + e1), ka, kb);               \
        float si1 = QB(v1, 0x00), sf1 = QB(v1, 0x55);                           \
        float tg1 = QB(v1, 0xAA), so1 = QB(v1, 0xFF);                           \
        c1 = fmaf(sf1, c1, si1 * tg1);                                          \
        float ec1 = __expf(-2.f * c1);                                          \
        float h1n = so1 * fmaf(2.f, __builtin_amdgcn_rcpf(1.f + ec1), -1.f);    \
        if (st) {                                                               \
            unsigned int uh = __float_as_uint(h1n);                             \
            fbh[fbase + (size_t)(TT) * 2048] = (unsigned short)(uh >> 16);      \
            fbl[fbase + (size_t)(TT) * 2048] =                                  \
                f2bf_rne(h1n - __uint_as_float(uh & 0xFFFF0000u));              \
        }                                                                       \
        _Pragma("unroll")                                                       \
        for (int m = 0; m < 16; ++m) h1[m] = RDLANE(h1n, 4 * m);                \
    }

        __syncthreads();   // wait for producer batch 0
        for (int tb = 0; tb < 64; ++tb) {
            const int bb = tb & 1;
            float zz[8];
            #pragma unroll
            for (int d = 0; d < 8; ++d) zz[d] = zbuf[sl][bb][d][lane];
            const int t0 = tb * 8;
            STEP1(zz[0], t0 + 0);
            STEP1(zz[1], t0 + 1);
            STEP1(zz[2], t0 + 2);
            STEP1(zz[3], t0 + 3);
            STEP1(zz[4], t0 + 4);
            STEP1(zz[5], t0 + 5);
            STEP1(zz[6], t0 + 6);
            STEP1(zz[7], t0 + 7);
            __syncthreads();
        }
#undef STEP1
    }
}

// ---------------------------------------------------------------------------
// Kernel 3/4: MFMA bf16 GEMM on pre-split hi/lo inputs. 64x64 tile,
// grid 16x16 = 256 blocks, 4 waves = 4 quadrants.  [unchanged]
// ---------------------------------------------------------------------------
__global__ __launch_bounds__(256) void k_fcmm(
    const unsigned short* __restrict__ Ahg, const unsigned short* __restrict__ Alg,
    const unsigned short* __restrict__ Bhg, const unsigned short* __restrict__ Blg,
    const float* __restrict__ bias,
    float* __restrict__ Cf, unsigned short* __restrict__ Chh,
    unsigned short* __restrict__ Chl,
    int N, int K)
{
    __shared__ unsigned short Ah[64 * FCS], Al[64 * FCS];
    __shared__ unsigned short Bh[64 * FCS], Bl[64 * FCS];
    const int t = threadIdx.x;
    const int lane = t & 63, w = t >> 6;
    const int wr = (w >> 1) * 32, wc = (w & 1) * 32;
    const int m0 = blockIdx.y * 64, n0 = blockIdx.x * 64;
    const int m16 = lane & 15, kb = (lane >> 4) * 8;
    const int sr = t >> 2, skg = (t & 3) * 8;

    f32x4 acc[2][2];
    #pragma unroll
    for (int mt = 0; mt < 2; ++mt)
        #pragma unroll
        for (int nt = 0; nt < 2; ++nt) {
            f32x4 z = {0.f, 0.f, 0.f, 0.f};
            acc[mt][nt] = z;
        }

    for (int kc = 0; kc < K; kc += 32) {
        size_t ga = (size_t)(m0 + sr) * K + kc + skg;
        size_t gb = (size_t)(n0 + sr) * K + kc + skg;
        *(uint4*)&Ah[sr * FCS + skg] = *(const uint4*)&Ahg[ga];
        *(uint4*)&Al[sr * FCS + skg] = *(const uint4*)&Alg[ga];
        *(uint4*)&Bh[sr * FCS + skg] = *(const uint4*)&Bhg[gb];
        *(uint4*)&Bl[sr * FCS + skg] = *(const uint4*)&Blg[gb];
        __syncthreads();

        bf16x8 afh[2], afl[2], bfh[2], bfl[2];
        #pragma unroll
        for (int mt = 0; mt < 2; ++mt) {
            int off = (wr + mt * 16 + m16) * FCS + kb;
            afh[mt] = *(const bf16x8*)&Ah[off];
            afl[mt] = *(const bf16x8*)&Al[off];
        }
        #pragma unroll
        for (int nt = 0; nt < 2; ++nt) {
            int off = (wc + nt * 16 + m16) * FCS + kb;
            bfh[nt] = *(const bf16x8*)&Bh[off];
            bfl[nt] = *(const bf16x8*)&Bl[off];
        }
        #pragma unroll
        for (int mt = 0; mt < 2; ++mt)
            #pragma unroll
            for (int nt = 0; nt < 2; ++nt) {
                acc[mt][nt] = __builtin_amdgcn_mfma_f32_16x16x32_bf16(afh[mt], bfh[nt], acc[mt][nt], 0, 0, 0);
                acc[mt][nt] = __builtin_amdgcn_mfma_f32_16x16x32_bf16(afl[mt], bfh[nt], acc[mt][nt], 0, 0, 0);
                acc[mt][nt] = __builtin_amdgcn_mfma_f32_16x16x32_bf16(afh[mt], bfl[nt], acc[mt][nt], 0, 0, 0);
            }
        __syncthreads();
    }

    #pragma unroll
    for (int mt = 0; mt < 2; ++mt)
        #pragma unroll
        for (int nt = 0; nt < 2; ++nt)
            #pragma unroll
            for (int r = 0; r < 4; ++r) {
                int rr = m0 + wr + mt * 16 + (lane >> 4) * 4 + r;
                int cc = n0 + wc + nt * 16 + m16;
                float v = acc[mt][nt][r] + bias[cc];
                v = (v > 0.f) ? v : 0.01f * v;
                if (Cf) {
                    Cf[(size_t)rr * N + cc] = v;
                } else {
                    unsigned int uv = __float_as_uint(v);
                    Chh[(size_t)rr * N + cc] = (unsigned short)(uv >> 16);
                    Chl[(size_t)rr * N + cc] =
                        f2bf_rne(v - __uint_as_float(uv & 0xFFFF0000u));
                }
            }
}

// ---------------------------------------------------------------------------
// Kernel 5: FC3 [1024,1024] @ [20,1024]^T + bias -> d_out [1024,20]
// ---------------------------------------------------------------------------
__global__ __launch_bounds__(256) void k_fc3(
    const float* __restrict__ A, const float* __restrict__ W,
    const float* __restrict__ bias, float* __restrict__ out)
{
    __shared__ float row[1024];
    __shared__ float red[20][8];
    const int m = blockIdx.x;
    const int t = threadIdx.x;
    #pragma unroll
    for (int r = 0; r < 4; ++r) row[r * 256 + t] = A[(size_t)m * 1024 + r * 256 + t];
    __syncthreads();
    if (t < 160) {
        int o = t >> 3, seg = t & 7;
        const float* w = W + (size_t)o * 1024 + seg * 128;
        const float* rr = &row[seg * 128];
        float s = 0.f;
        for (int kk = 0; kk < 128; ++kk) s += rr[kk] * w[kk];
        red[o][seg] = s;
    }
    __syncthreads();
    if (t < 20) {
        float s = bias[t];
        #pragma unroll
        for (int seg = 0; seg < 8; ++seg) s += red[t][seg];
        out[(size_t)m * 20 + t] = s;
    }
}

// ---------------------------------------------------------------------------
extern "C" void kernel_launch(void* const* d_in, const int* in_sizes, int n_in,
                              void* d_out, int out_size, void* d_ws, size_t ws_size,
                              hipStream_t stream) {
    const float* in1    = (const float*)d_in[0];
    const float* in2    = (const float*)d_in[1];
    const float* w_x_q  = (const float*)d_in[2];
    const float* w_x_k  = (const float*)d_in[3];
    const float* w_y_q  = (const float*)d_in[4];
    const float* w_y_k  = (const float*)d_in[5];
    const float* posemb = (const float*)d_in[6];
    const float* conv_w = (const float*)d_in[7];
    const float* conv_b = (const float*)d_in[8];
    const float* bn_g   = (const float*)d_in[9];
    const float* bn_b   = (const float*)d_in[10];
    const float* bn_m   = (const float*)d_in[11];
    const float* bn_v   = (const float*)d_in[12];
    const float* Wih0   = (const float*)d_in[13];
    const float* Whh0   = (const float*)d_in[14];
    const float* bih0   = (const float*)d_in[15];
    const float* bhh0   = (const float*)d_in[16];
    const float* Wih1   = (const float*)d_in[17];
    const float* Whh1   = (const float*)d_in[18];
    const float* bih1   = (const float*)d_in[19];
    const float* bhh1   = (const float*)d_in[20];
    const float* fc1w   = (const float*)d_in[21];
    const float* fc1b   = (const float*)d_in[22];
    const float* fc2w   = (const float*)d_in[23];
    const float* fc2b   = (const float*)d_in[24];
    const float* fc3w   = (const float*)d_in[25];
    const float* fc3b   = (const float*)d_in[26];
    float* out = (float*)d_out;

    float* ws = (float*)d_ws;
    float* pre0            = ws;                               // 8,466,432
    unsigned short* fbh    = (unsigned short*)(ws + 8466432);  // 2,097,152 us
    unsigned short* fbl    = (unsigned short*)(ws + 9515008);
    unsigned short* f1h    = (unsigned short*)(ws + 10563584); // 1,048,576 us
    unsigned short* f1l    = (unsigned short*)(ws + 11087872);
    float* f2              = ws + 11612160;                    // 1,048,576 f
    unsigned short* w1h    = (unsigned short*)(ws + 12660736); // 2,097,152 us
    unsigned short* w1l    = (unsigned short*)(ws + 13709312);
    unsigned short* w2h    = (unsigned short*)(ws + 14757888); // 1,048,576 us
    unsigned short* w2l    = (unsigned short*)(ws + 15282176);
    unsigned short* Wfh    = (unsigned short*)(ws + 15806464); // 30,720 us
    unsigned short* Wfl    = (unsigned short*)(ws + 15821824);

    k_permW<<<120, 256, 0, stream>>>(Wih0, Wfh, Wfl);
    k_cvt<<<2048, 256, 0, stream>>>(fc1w, w1h, w1l, 524288);
    k_cvt<<<1024, 256, 0, stream>>>(fc2w, w2h, w2l, 262144);
    k_attn_conv<<<1024, 256, 0, stream>>>(in1, in2, w_x_q, w_x_k, w_y_q, w_y_k,
                                          posemb, conv_w, conv_b, bn_g, bn_b,
                                          bn_m, bn_v, Wfh, Wfl, pre0);
    k_lstm<<<64, 512, 0, stream>>>(pre0, Whh0, Wih1, Whh1,
                                   bih0, bhh0, bih1, bhh1, fbh, fbl);
    dim3 gfc(16, 16);
    k_fcmm<<<gfc, 256, 0, stream>>>(fbh, fbl, w1h, w1l, fc1b,
                                    nullptr, f1h, f1l, 1024, 2048);
    k_fcmm<<<gfc, 256, 0, stream>>>(f1h, f1l, w2h, w2l, fc2b,
                                    f2, nullptr, nullptr, 1024, 1024);
    k_fc3<<<1024, 256, 0, stream>>>(f2, fc3w, fc3b, out);
}

// Round 14
// 230.255 us; speedup vs baseline: 1.2803x; 1.2803x over previous
//
#include <hip/hip_runtime.h>

// Problem constants: B=512, L=128, N=64, H=16, PW=30, FEAT=480
#define LSX 65    // xs row stride (64+1)
#define FCS 40    // fcmm LDS row stride (32+8 ushorts)

typedef __bf16 bf16x8 __attribute__((ext_vector_type(8)));
typedef float  f32x4  __attribute__((ext_vector_type(4)));

__device__ __forceinline__ unsigned short f2bf_rne(float x) {
    unsigned int u = __float_as_uint(x);
    unsigned int r = u + 0x7FFFu + ((u >> 16) & 1u);
    return (unsigned short)(r >> 16);
}

// quad_perm broadcast of quad-lane Q (DPP ctrl = Q*0x55)
#define QB(x, C) __uint_as_float((unsigned)__builtin_amdgcn_update_dpp( \
        0, (int)__float_as_uint(x), (C), 0xF, 0xF, false))
#define RDLANE(x, L) __uint_as_float((unsigned)__builtin_amdgcn_readlane( \
        (int)__float_as_uint(x), (L)))

// ---------------------------------------------------------------------------
// Kernel 0: Wih0 [64,480] -> MFMA B-fragment layout, bf16 hi/lo
// ---------------------------------------------------------------------------
__global__ __launch_bounds__(256) void k_permW(const float* __restrict__ Wih0,
                                               unsigned short* __restrict__ Wfh,
                                               unsigned short* __restrict__ Wfl)
{
    int idx = blockIdx.x * 256 + threadIdx.x;     // < 30720
    int j = idx & 7, lane = (idx >> 3) & 63, nt = (idx >> 9) & 3, ch = idx >> 11;
    int g = nt * 16 + (lane & 15);
    int k = (lane >> 4) * 8 + j;
    int f = ch * 32 + k, q = f >> 4, h = f & 15;
    float v = Wih0[g * 480 + h * 30 + q];
    unsigned int uv = __float_as_uint(v);
    Wfh[idx] = (unsigned short)(uv >> 16);
    Wfl[idx] = f2bf_rne(v - __uint_as_float(uv & 0xFFFF0000u));
}

// ---------------------------------------------------------------------------
// Kernel 0b: generic fp32 -> bf16 hi/lo split (per float4)
// ---------------------------------------------------------------------------
__global__ __launch_bounds__(256) void k_cvt(const float* __restrict__ in,
                                             unsigned short* __restrict__ oh,
                                             unsigned short* __restrict__ ol,
                                             int n4)
{
    int i = blockIdx.x * 256 + threadIdx.x;
    if (i >= n4) return;
    float4 v = ((const float4*)in)[i];
    float vv[4] = {v.x, v.y, v.z, v.w};
    unsigned short hs[4], ls[4];
    #pragma unroll
    for (int e = 0; e < 4; ++e) {
        unsigned int u = __float_as_uint(vv[e]);
        hs[e] = (unsigned short)(u >> 16);
        ls[e] = f2bf_rne(vv[e] - __uint_as_float(u & 0xFFFF0000u));
    }
    uint2 ph = make_uint2((unsigned)hs[0] | ((unsigned)hs[1] << 16),
                          (unsigned)hs[2] | ((unsigned)hs[3] << 16));
    uint2 pl = make_uint2((unsigned)ls[0] | ((unsigned)ls[1] << 16),
                          (unsigned)ls[2] | ((unsigned)ls[3] << 16));
    *(uint2*)&oh[i * 4] = ph;
    *(uint2*)&ol[i * 4] = pl;
}

// ---------------------------------------------------------------------------
// Kernel 1: dual-axis attention + conv/bn/pool + MFMA GEMM. [round-12 verbatim]
// ---------------------------------------------------------------------------
__global__ __launch_bounds__(256, 4) void k_attn_conv(
    const float* __restrict__ x1, const float* __restrict__ x2,
    const float* __restrict__ w_x_q, const float* __restrict__ w_x_k,
    const float* __restrict__ w_y_q, const float* __restrict__ w_y_k,
    const float* __restrict__ pos_emb,
    const float* __restrict__ conv_w, const float* __restrict__ conv_b,
    const float* __restrict__ bn_g, const float* __restrict__ bn_b,
    const float* __restrict__ bn_m, const float* __restrict__ bn_v,
    const unsigned short* __restrict__ Wfh, const unsigned short* __restrict__ Wfl,
    float* __restrict__ pre0)
{
    __shared__ float xs[128 * LSX];
    __shared__ float xkp[2][64], ykv[128], uu[64], vv[128];
    __shared__ float sxs[128], sysp[2][64], sys[64];
    __shared__ float cw[16][4], cbs[16], bnsh[16];

    const int bg = blockIdx.x;
    const int t  = threadIdx.x;
    const float* x = (bg < 512 ? x1 : x2) + (size_t)(bg & 511) * 8192;

    #pragma unroll
    for (int r = 0; r < 32; ++r) {
        int pos = r * 256 + t;
        xs[(pos >> 6) * LSX + (pos & 63)] = x[pos];
    }
    if (t < 16) {
        float sc = bn_g[t] * rsqrtf(bn_v[t] + 1e-5f);   // > 0 for given inputs
        bnsh[t] = bn_b[t] - bn_m[t] * sc;
        cbs[t]  = conv_b[t] * sc;
        cw[t][0] = conv_w[t * 4 + 0] * sc; cw[t][1] = conv_w[t * 4 + 1] * sc;
        cw[t][2] = conv_w[t * 4 + 2] * sc; cw[t][3] = conv_w[t * 4 + 3] * sc;
    }
    __syncthreads();

    if (t < 128) {
        int n = t & 63, hf = t >> 6;
        const float* base = &xs[hf * 64 * LSX + n];
        const float* wk = w_x_k + hf * 64;
        float s0 = 0.f, s1 = 0.f, s2 = 0.f, s3 = 0.f;
        for (int l = 0; l < 64; l += 4) {
            s0 += base[(l + 0) * LSX] * wk[l + 0];
            s1 += base[(l + 1) * LSX] * wk[l + 1];
            s2 += base[(l + 2) * LSX] * wk[l + 2];
            s3 += base[(l + 3) * LSX] * wk[l + 3];
        }
        xkp[hf][n] = (s0 + s1) + (s2 + s3);
    } else {
        int l = t - 128;
        const float* row = &xs[l * LSX];
        float s0 = 0.f, s1 = 0.f, s2 = 0.f, s3 = 0.f;
        for (int n = 0; n < 64; n += 4) {
            s0 += w_y_k[n + 0] * row[n + 0];
            s1 += w_y_k[n + 1] * row[n + 1];
            s2 += w_y_k[n + 2] * row[n + 2];
            s3 += w_y_k[n + 3] * row[n + 3];
        }
        ykv[l] = (s0 + s1) + (s2 + s3);
    }
    __syncthreads();

    if (t < 64) {
        const float* wq = w_x_q + t * 64;
        float s0 = 0.f, s1 = 0.f, s2 = 0.f, s3 = 0.f;
        for (int n = 0; n < 64; n += 4) {
            s0 += wq[n + 0] * (xkp[0][n + 0] + xkp[1][n + 0]);
            s1 += wq[n + 1] * (xkp[0][n + 1] + xkp[1][n + 1]);
            s2 += wq[n + 2] * (xkp[0][n + 2] + xkp[1][n + 2]);
            s3 += wq[n + 3] * (xkp[0][n + 3] + xkp[1][n + 3]);
        }
        uu[t] = (s0 + s1) + (s2 + s3);
    } else if (t < 192) {
        int m = t - 64;
        float s0 = 0.f, s1 = 0.f, s2 = 0.f, s3 = 0.f;
        for (int l = 0; l < 128; l += 4) {
            s0 += ykv[l + 0] * w_y_q[(l + 0) * 128 + m];
            s1 += ykv[l + 1] * w_y_q[(l + 1) * 128 + m];
            s2 += ykv[l + 2] * w_y_q[(l + 2) * 128 + m];
            s3 += ykv[l + 3] * w_y_q[(l + 3) * 128 + m];
        }
        vv[m] = (s0 + s1) + (s2 + s3);
    }
    __syncthreads();

    if (t < 128) {
        const float* row = &xs[t * LSX];
        float s0 = 0.f, s1 = 0.f, s2 = 0.f, s3 = 0.f;
        for (int m = 0; m < 64; m += 4) {
            s0 += row[m + 0] * uu[m + 0];
            s1 += row[m + 1] * uu[m + 1];
            s2 += row[m + 2] * uu[m + 2];
            s3 += row[m + 3] * uu[m + 3];
        }
        sxs[t] = (s0 + s1) + (s2 + s3);
    } else {
        int n = (t - 128) & 63, hf = (t - 128) >> 6;
        const float* base = &xs[hf * 64 * LSX + n];
        const float* vp = vv + hf * 64;
        float s0 = 0.f, s1 = 0.f, s2 = 0.f, s3 = 0.f;
        for (int m = 0; m < 64; m += 4) {
            s0 += vp[m + 0] * base[(m + 0) * LSX];
            s1 += vp[m + 1] * base[(m + 1) * LSX];
            s2 += vp[m + 2] * base[(m + 2) * LSX];
            s3 += vp[m + 3] * base[(m + 3) * LSX];
        }
        sysp[hf][n] = (s0 + s1) + (s2 + s3);
    }
    __syncthreads();

    if (t < 64) {
        float a = sxs[t], b = sxs[t + 64];
        float mx = fmaxf(a, b);
        #pragma unroll
        for (int d = 32; d > 0; d >>= 1) mx = fmaxf(mx, __shfl_xor(mx, d, 64));
        float e0 = __expf(a - mx), e1 = __expf(b - mx);
        float s = e0 + e1;
        #pragma unroll
        for (int d = 32; d > 0; d >>= 1) s += __shfl_xor(s, d, 64);
        float r = 10.f / s;
        sxs[t] = e0 * r; sxs[t + 64] = e1 * r;
    } else if (t < 128) {
        int n = t - 64;
        float a = sysp[0][n] + sysp[1][n];
        float mx = a;
        #pragma unroll
        for (int d = 32; d > 0; d >>= 1) mx = fmaxf(mx, __shfl_xor(mx, d, 64));
        float e = __expf(a - mx);
        float s = e;
        #pragma unroll
        for (int d = 32; d > 0; d >>= 1) s += __shfl_xor(s, d, 64);
        sys[n] = e * (10.f / s);
    }
    __syncthreads();

    #pragma unroll
    for (int r = 0; r < 32; ++r) {
        int pos = r * 256 + t;
        int l = pos >> 6, n = pos & 63;
        xs[l * LSX + n] = xs[l * LSX + n] * sxs[l] * sys[n] + pos_emb[pos];
    }
    __syncthreads();

    const int lane = t & 63, w = t >> 6;
    const int m16 = lane & 15, kq = lane >> 4;
    const int hb = (kq & 1) * 8;
    const int qoff = kq >> 1;

    float cwr0[8], cwr1[8], cwr2[8], cwr3[8], cbr[8], bhr[8];
    #pragma unroll
    for (int j = 0; j < 8; ++j) {
        cwr0[j] = cw[hb + j][0]; cwr1[j] = cw[hb + j][1];
        cwr2[j] = cw[hb + j][2]; cwr3[j] = cw[hb + j][3];
        cbr[j] = cbs[hb + j]; bhr[j] = bnsh[hb + j];
    }

    f32x4 acc[2][4];
    #pragma unroll
    for (int mt = 0; mt < 2; ++mt)
        #pragma unroll
        for (int nt = 0; nt < 4; ++nt) {
            f32x4 z = {0.f, 0.f, 0.f, 0.f};
            acc[mt][nt] = z;
        }

    for (int ch = 0; ch < 15; ++ch) {
        bf16x8 ah[2], al[2];
        const int q2 = 2 * (2 * ch + qoff);
        #pragma unroll
        for (int mt = 0; mt < 2; ++mt) {
            int row = w * 32 + mt * 16 + m16;
            const float* xr = &xs[row * LSX + q2];
            float o0 = xr[0], o1 = xr[1], o2 = xr[2], o3 = xr[3], o4 = xr[4];
            union { unsigned short us[8]; bf16x8 bv; } vh, vl;
            #pragma unroll
            for (int j = 0; j < 8; ++j) {
                float a = fmaf(o0, cwr0[j], fmaf(o1, cwr1[j], fmaf(o2, cwr2[j], fmaf(o3, cwr3[j], cbr[j]))));
                float b = fmaf(o1, cwr0[j], fmaf(o2, cwr1[j], fmaf(o3, cwr2[j], fmaf(o4, cwr3[j], cbr[j]))));
                float v = fmaxf(fmaxf(a, 0.f), fmaxf(b, 0.f)) + bhr[j];
                unsigned int uv = __float_as_uint(v);
                vh.us[j] = (unsigned short)(uv >> 16);
                vl.us[j] = f2bf_rne(v - __uint_as_float(uv & 0xFFFF0000u));
            }
            ah[mt] = vh.bv; al[mt] = vl.bv;
        }
        #pragma unroll
        for (int nh = 0; nh < 2; ++nh) {
            bf16x8 bh[2], bl[2];
            #pragma unroll
            for (int ni = 0; ni < 2; ++ni) {
                int o = ((ch * 4 + nh * 2 + ni) * 64 + lane) * 8;
                bh[ni] = *(const bf16x8*)&Wfh[o];
                bl[ni] = *(const bf16x8*)&Wfl[o];
            }
            #pragma unroll
            for (int mt = 0; mt < 2; ++mt)
                #pragma unroll
                for (int ni = 0; ni < 2; ++ni) {
                    int nt = nh * 2 + ni;
                    acc[mt][nt] = __builtin_amdgcn_mfma_f32_16x16x32_bf16(ah[mt], bh[ni], acc[mt][nt], 0, 0, 0);
                    acc[mt][nt] = __builtin_amdgcn_mfma_f32_16x16x32_bf16(al[mt], bh[ni], acc[mt][nt], 0, 0, 0);
                    acc[mt][nt] = __builtin_amdgcn_mfma_f32_16x16x32_bf16(ah[mt], bl[ni], acc[mt][nt], 0, 0, 0);
                }
        }
    }

    #pragma unroll
    for (int mt = 0; mt < 2; ++mt)
        #pragma unroll
        for (int nt = 0; nt < 4; ++nt)
            #pragma unroll
            for (int r = 0; r < 4; ++r) {
                int row = w * 32 + mt * 16 + (lane >> 4) * 4 + r;
                int col = nt * 16 + m16;
                pre0[(size_t)bg * 8192 + row * 64 + col] = acc[mt][nt][r];
            }
}

// ---------------------------------------------------------------------------
// Kernel 2: producer-consumer 2-wave LSTM, barrier-paired double buffering,
// batch = 16 steps per barrier (32 barrier pairs). One block per sequence.
// ---------------------------------------------------------------------------
__global__ __launch_bounds__(128) void k_lstm(
    const float* __restrict__ pre0,
    const float* __restrict__ Whh0,
    const float* __restrict__ Wih1, const float* __restrict__ Whh1,
    const float* __restrict__ bih0, const float* __restrict__ bhh0,
    const float* __restrict__ bih1, const float* __restrict__ bhh1,
    unsigned short* __restrict__ fbh, unsigned short* __restrict__ fbl)
{
    __shared__ float zbuf[2][16][64];

    const int blk = blockIdx.x;
    const int i = blk >> 7, j = blk & 127;
    const int tid = threadIdx.x;
    const int lane = tid & 63;
    const int wv = tid >> 6;
    const int a = lane & 3, u = lane >> 2;
    const int row = a * 16 + u;          // torch gate-row index
    const float pm = (a == 2) ? -2.f : -1.f;
    const float ka = (a == 2) ?  2.f :  1.f;
    const float kb = (a == 2) ? -1.f :  0.f;

    if (wv == 0) {
        float w0[16], wi1[16];
        #pragma unroll
        for (int m = 0; m < 16; ++m) {
            w0[m]  = Whh0[row * 16 + m];
            wi1[m] = Wih1[row * 16 + m];
        }
        const float b0 = bih0[row] + bhh0[row];
        float h0[16];
        #pragma unroll
        for (int m = 0; m < 16; ++m) h0[m] = 0.f;
        float c0 = 0.f;

        const float* pp = pre0 + (size_t)i * 4194304 + (size_t)j * 64 + row;
        float pf[16];
        #pragma unroll
        for (int d = 0; d < 16; ++d) pf[d] = pp[(size_t)d * 8192];

#define STEP0(PRE, DD, BB)                                                      \
    {                                                                           \
        float sA = 0.f, sB = 0.f, sC = 0.f, sD = 0.f;                           \
        _Pragma("unroll")                                                       \
        for (int m = 0; m < 4; ++m) {                                           \
            sA += h0[m]      * w0[m];                                           \
            sB += h0[m + 4]  * w0[m + 4];                                       \
            sC += h0[m + 8]  * w0[m + 8];                                       \
            sD += h0[m + 12] * w0[m + 12];                                      \
        }                                                                       \
        float g0 = (PRE) + b0 + ((sA + sB) + (sC + sD));                        \
        float e0 = __expf(pm * g0);                                             \
        float v0 = fmaf(__builtin_amdgcn_rcpf(1.f + e0), ka, kb);               \
        float si = QB(v0, 0x00), sf = QB(v0, 0x55);                             \
        float tg = QB(v0, 0xAA), so = QB(v0, 0xFF);                             \
        c0 = fmaf(sf, c0, si * tg);                                             \
        float ec = __expf(-2.f * c0);                                           \
        float h0n = so * fmaf(2.f, __builtin_amdgcn_rcpf(1.f + ec), -1.f);      \
        float hn[16];                                                           \
        _Pragma("unroll")                                                       \
        for (int m = 0; m < 16; ++m) hn[m] = RDLANE(h0n, 4 * m);                \
        float zA = 0.f, zB = 0.f, zC = 0.f, zD = 0.f;                           \
        _Pragma("unroll")                                                       \
        for (int m = 0; m < 4; ++m) {                                           \
            zA += hn[m]      * wi1[m];                                          \
            zB += hn[m + 4]  * wi1[m + 4];                                      \
            zC += hn[m + 8]  * wi1[m + 8];                                      \
            zD += hn[m + 12] * wi1[m + 12];                                     \
        }                                                                       \
        zbuf[BB][DD][lane] = (zA + zB) + (zC + zD);                             \
        _Pragma("unroll")                                                       \
        for (int m = 0; m < 16; ++m) h0[m] = hn[m];                             \
    }

        for (int tb = 0; tb < 32; ++tb) {
            const int bb = tb & 1;
            float nx[16];
            #pragma unroll
            for (int d = 0; d < 16; ++d)
                nx[d] = pp[(size_t)(tb * 16 + 16 + d) * 8192];
            STEP0(pf[0],  0,  bb);
            STEP0(pf[1],  1,  bb);
            STEP0(pf[2],  2,  bb);
            STEP0(pf[3],  3,  bb);
            STEP0(pf[4],  4,  bb);
            STEP0(pf[5],  5,  bb);
            STEP0(pf[6],  6,  bb);
            STEP0(pf[7],  7,  bb);
            STEP0(pf[8],  8,  bb);
            STEP0(pf[9],  9,  bb);
            STEP0(pf[10], 10, bb);
            STEP0(pf[11], 11, bb);
            STEP0(pf[12], 12, bb);
            STEP0(pf[13], 13, bb);
            STEP0(pf[14], 14, bb);
            STEP0(pf[15], 15, bb);
            #pragma unroll
            for (int d = 0; d < 16; ++d) pf[d] = nx[d];
            __syncthreads();
        }
        __syncthreads();   // pair with consumer's initial barrier
#undef STEP0
    } else {
        float wh1[16];
        #pragma unroll
        for (int m = 0; m < 16; ++m) wh1[m] = Whh1[row * 16 + m];
        const float b1 = bih1[row] + bhh1[row];
        float h1[16];
        #pragma unroll
        for (int m = 0; m < 16; ++m) h1[m] = 0.f;
        float c1 = 0.f;

        const size_t fbase = (size_t)i * 1048576 + (size_t)j * 16 + u;
        const bool st = (a == 0);

#define STEP1(ZZ, TT)                                                           \
    {                                                                           \
        float tA = 0.f, tB = 0.f, tC = 0.f, tD = 0.f;                           \
        _Pragma("unroll")                                                       \
        for (int m = 0; m < 4; ++m) {                                           \
            tA += h1[m]      * wh1[m];                                          \
            tB += h1[m + 4]  * wh1[m + 4];                                      \
            tC += h1[m + 8]  * wh1[m + 8];                                      \
            tD += h1[m + 12] * wh1[m + 12];                                     \
        }                                                                       \
        float g1 = (ZZ) + b1 + ((tA + tB) + (tC + tD));                         \
        float e1 = __expf(pm * g1);                                             \
        float v1 = fmaf(__builtin_amdgcn_rcpf(1.f + e1), ka, kb);               \
        float si1 = QB(v1, 0x00), sf1 = QB(v1, 0x55);                           \
        float tg1 = QB(v1, 0xAA), so1 = QB(v1, 0xFF);                           \
        c1 = fmaf(sf1, c1, si1 * tg1);                                          \
        float ec1 = __expf(-2.f * c1);                                          \
        float h1n = so1 * fmaf(2.f, __builtin_amdgcn_rcpf(1.f + ec1), -1.f);    \
        if (st) {                                                               \
            unsigned int uh = __float_as_uint(h1n);                             \
            fbh[fbase + (size_t)(TT) * 2048] = (unsigned short)(uh >> 16);      \
            fbl[fbase + (size_t)(TT) * 2048] =                                  \
                f2bf_rne(h1n - __uint_as_float(uh & 0xFFFF0000u));              \
        }                                                                       \
        _Pragma("unroll")                                                       \
        for (int m = 0; m < 16; ++m) h1[m] = RDLANE(h1n, 4 * m);                \
    }

        __syncthreads();   // wait for batch 0
        for (int tb = 0; tb < 32; ++tb) {
            const int bb = tb & 1;
            float zz[16];
            #pragma unroll
            for (int d = 0; d < 16; ++d) zz[d] = zbuf[bb][d][lane];
            const int t0 = tb * 16;
            STEP1(zz[0],  t0 + 0);
            STEP1(zz[1],  t0 + 1);
            STEP1(zz[2],  t0 + 2);
            STEP1(zz[3],  t0 + 3);
            STEP1(zz[4],  t0 + 4);
            STEP1(zz[5],  t0 + 5);
            STEP1(zz[6],  t0 + 6);
            STEP1(zz[7],  t0 + 7);
            STEP1(zz[8],  t0 + 8);
            STEP1(zz[9],  t0 + 9);
            STEP1(zz[10], t0 + 10);
            STEP1(zz[11], t0 + 11);
            STEP1(zz[12], t0 + 12);
            STEP1(zz[13], t0 + 13);
            STEP1(zz[14], t0 + 14);
            STEP1(zz[15], t0 + 15);
            __syncthreads();
        }
#undef STEP1
    }
}

// ---------------------------------------------------------------------------
// Kernel 3/4: MFMA bf16 GEMM on pre-split hi/lo inputs. 64x64 tile,
// grid 16x16 = 256 blocks, 4 waves = 4 quadrants.  [unchanged]
// ---------------------------------------------------------------------------
__global__ __launch_bounds__(256) void k_fcmm(
    const unsigned short* __restrict__ Ahg, const unsigned short* __restrict__ Alg,
    const unsigned short* __restrict__ Bhg, const unsigned short* __restrict__ Blg,
    const float* __restrict__ bias,
    float* __restrict__ Cf, unsigned short* __restrict__ Chh,
    unsigned short* __restrict__ Chl,
    int N, int K)
{
    __shared__ unsigned short Ah[64 * FCS], Al[64 * FCS];
    __shared__ unsigned short Bh[64 * FCS], Bl[64 * FCS];
    const int t = threadIdx.x;
    const int lane = t & 63, w = t >> 6;
    const int wr = (w >> 1) * 32, wc = (w & 1) * 32;
    const int m0 = blockIdx.y * 64, n0 = blockIdx.x * 64;
    const int m16 = lane & 15, kb = (lane >> 4) * 8;
    const int sr = t >> 2, skg = (t & 3) * 8;

    f32x4 acc[2][2];
    #pragma unroll
    for (int mt = 0; mt < 2; ++mt)
        #pragma unroll
        for (int nt = 0; nt < 2; ++nt) {
            f32x4 z = {0.f, 0.f, 0.f, 0.f};
            acc[mt][nt] = z;
        }

    for (int kc = 0; kc < K; kc += 32) {
        size_t ga = (size_t)(m0 + sr) * K + kc + skg;
        size_t gb = (size_t)(n0 + sr) * K + kc + skg;
        *(uint4*)&Ah[sr * FCS + skg] = *(const uint4*)&Ahg[ga];
        *(uint4*)&Al[sr * FCS + skg] = *(const uint4*)&Alg[ga];
        *(uint4*)&Bh[sr * FCS + skg] = *(const uint4*)&Bhg[gb];
        *(uint4*)&Bl[sr * FCS + skg] = *(const uint4*)&Blg[gb];
        __syncthreads();

        bf16x8 afh[2], afl[2], bfh[2], bfl[2];
        #pragma unroll
        for (int mt = 0; mt < 2; ++mt) {
            int off = (wr + mt * 16 + m16) * FCS + kb;
            afh[mt] = *(const bf16x8*)&Ah[off];
            afl[mt] = *(const bf16x8*)&Al[off];
        }
        #pragma unroll
        for (int nt = 0; nt < 2; ++nt) {
            int off = (wc + nt * 16 + m16) * FCS + kb;
            bfh[nt] = *(const bf16x8*)&Bh[off];
            bfl[nt] = *(const bf16x8*)&Bl[off];
        }
        #pragma unroll
        for (int mt = 0; mt < 2; ++mt)
            #pragma unroll
            for (int nt = 0; nt < 2; ++nt) {
                acc[mt][nt] = __builtin_amdgcn_mfma_f32_16x16x32_bf16(afh[mt], bfh[nt], acc[mt][nt], 0, 0, 0);
                acc[mt][nt] = __builtin_amdgcn_mfma_f32_16x16x32_bf16(afl[mt], bfh[nt], acc[mt][nt], 0, 0, 0);
                acc[mt][nt] = __builtin_amdgcn_mfma_f32_16x16x32_bf16(afh[mt], bfl[nt], acc[mt][nt], 0, 0, 0);
            }
        __syncthreads();
    }

    #pragma unroll
    for (int mt = 0; mt < 2; ++mt)
        #pragma unroll
        for (int nt = 0; nt < 2; ++nt)
            #pragma unroll
            for (int r = 0; r < 4; ++r) {
                int rr = m0 + wr + mt * 16 + (lane >> 4) * 4 + r;
                int cc = n0 + wc + nt * 16 + m16;
                float v = acc[mt][nt][r] + bias[cc];
                v = (v > 0.f) ? v : 0.01f * v;
                if (Cf) {
                    Cf[(size_t)rr * N + cc] = v;
                } else {
                    unsigned int uv = __float_as_uint(v);
                    Chh[(size_t)rr * N + cc] = (unsigned short)(uv >> 16);
                    Chl[(size_t)rr * N + cc] =
                        f2bf_rne(v - __uint_as_float(uv & 0xFFFF0000u));
                }
            }
}

// ---------------------------------------------------------------------------
// Kernel 5: FC3 [1024,1024] @ [20,1024]^T + bias -> d_out [1024,20]
// ---------------------------------------------------------------------------
__global__ __launch_bounds__(256) void k_fc3(
    const float* __restrict__ A, const float* __restrict__ W,
    const float* __restrict__ bias, float* __restrict__ out)
{
    __shared__ float row[1024];
    __shared__ float red[20][8];
    const int m = blockIdx.x;
    const int t = threadIdx.x;
    #pragma unroll
    for (int r = 0; r < 4; ++r) row[r * 256 + t] = A[(size_t)m * 1024 + r * 256 + t];
    __syncthreads();
    if (t < 160) {
        int o = t >> 3, seg = t & 7;
        const float* w = W + (size_t)o * 1024 + seg * 128;
        const float* rr = &row[seg * 128];
        float s = 0.f;
        for (int kk = 0; kk < 128; ++kk) s += rr[kk] * w[kk];
        red[o][seg] = s;
    }
    __syncthreads();
    if (t < 20) {
        float s = bias[t];
        #pragma unroll
        for (int seg = 0; seg < 8; ++seg) s += red[t][seg];
        out[(size_t)m * 20 + t] = s;
    }
}

// ---------------------------------------------------------------------------
extern "C" void kernel_launch(void* const* d_in, const int* in_sizes, int n_in,
                              void* d_out, int out_size, void* d_ws, size_t ws_size,
                              hipStream_t stream) {
    const float* in1    = (const float*)d_in[0];
    const float* in2    = (const float*)d_in[1];
    const float* w_x_q  = (const float*)d_in[2];
    const float* w_x_k  = (const float*)d_in[3];
    const float* w_y_q  = (const float*)d_in[4];
    const float* w_y_k  = (const float*)d_in[5];
    const float* posemb = (const float*)d_in[6];
    const float* conv_w = (const float*)d_in[7];
    const float* conv_b = (const float*)d_in[8];
    const float* bn_g   = (const float*)d_in[9];
    const float* bn_b   = (const float*)d_in[10];
    const float* bn_m   = (const float*)d_in[11];
    const float* bn_v   = (const float*)d_in[12];
    const float* Wih0   = (const float*)d_in[13];
    const float* Whh0   = (const float*)d_in[14];
    const float* bih0   = (const float*)d_in[15];
    const float* bhh0   = (const float*)d_in[16];
    const float* Wih1   = (const float*)d_in[17];
    const float* Whh1   = (const float*)d_in[18];
    const float* bih1   = (const float*)d_in[19];
    const float* bhh1   = (const float*)d_in[20];
    const float* fc1w   = (const float*)d_in[21];
    const float* fc1b   = (const float*)d_in[22];
    const float* fc2w   = (const float*)d_in[23];
    const float* fc2b   = (const float*)d_in[24];
    const float* fc3w   = (const float*)d_in[25];
    const float* fc3b   = (const float*)d_in[26];
    float* out = (float*)d_out;

    float* ws = (float*)d_ws;
    float* pre0            = ws;                               // 8,466,432
    unsigned short* fbh    = (unsigned short*)(ws + 8466432);  // 2,097,152 us
    unsigned short* fbl    = (unsigned short*)(ws + 9515008);
    unsigned short* f1h    = (unsigned short*)(ws + 10563584); // 1,048,576 us
    unsigned short* f1l    = (unsigned short*)(ws + 11087872);
    float* f2              = ws + 11612160;                    // 1,048,576 f
    unsigned short* w1h    = (unsigned short*)(ws + 12660736); // 2,097,152 us
    unsigned short* w1l    = (unsigned short*)(ws + 13709312);
    unsigned short* w2h    = (unsigned short*)(ws + 14757888); // 1,048,576 us
    unsigned short* w2l    = (unsigned short*)(ws + 15282176);
    unsigned short* Wfh    = (unsigned short*)(ws + 15806464); // 30,720 us
    unsigned short* Wfl    = (unsigned short*)(ws + 15821824);

    k_permW<<<120, 256, 0, stream>>>(Wih0, Wfh, Wfl);
    k_cvt<<<2048, 256, 0, stream>>>(fc1w, w1h, w1l, 524288);
    k_cvt<<<1024, 256, 0, stream>>>(fc2w, w2h, w2l, 262144);
    k_attn_conv<<<1024, 256, 0, stream>>>(in1, in2, w_x_q, w_x_k, w_y_q, w_y_k,
                                          posemb, conv_w, conv_b, bn_g, bn_b,
                                          bn_m, bn_v, Wfh, Wfl, pre0);
    k_lstm<<<256, 128, 0, stream>>>(pre0, Whh0, Wih1, Whh1,
                                    bih0, bhh0, bih1, bhh1, fbh, fbl);
    dim3 gfc(16, 16);
    k_fcmm<<<gfc, 256, 0, stream>>>(fbh, fbl, w1h, w1l, fc1b,
                                    nullptr, f1h, f1l, 1024, 2048);
    k_fcmm<<<gfc, 256, 0, stream>>>(f1h, f1l, w2h, w2l, fc2b,
                                    f2, nullptr, nullptr, 1024, 1024);
    k_fc3<<<1024, 256, 0, stream>>>(f2, fc3w, fc3b, out);
}

// Round 15
// 229.708 us; speedup vs baseline: 1.2834x; 1.0024x over previous
//
#include <hip/hip_runtime.h>

// Problem constants: B=512, L=128, N=64, H=16, PW=30, FEAT=480
#define LSX 65    // xs row stride (64+1)
#define FCS 40    // fcmm LDS row stride (32+8 ushorts)

typedef __bf16 bf16x8 __attribute__((ext_vector_type(8)));
typedef float  f32x4  __attribute__((ext_vector_type(4)));

__device__ __forceinline__ unsigned short f2bf_rne(float x) {
    unsigned int u = __float_as_uint(x);
    unsigned int r = u + 0x7FFFu + ((u >> 16) & 1u);
    return (unsigned short)(r >> 16);
}

// quad_perm broadcast of quad-lane Q (DPP ctrl = Q*0x55)
#define QB(x, C) __uint_as_float((unsigned)__builtin_amdgcn_update_dpp( \
        0, (int)__float_as_uint(x), (C), 0xF, 0xF, false))
#define RDLANE(x, L) __uint_as_float((unsigned)__builtin_amdgcn_readlane( \
        (int)__float_as_uint(x), (L)))

// ---------------------------------------------------------------------------
// Kernel 0: Wih0 [64,480] -> MFMA B-fragment layout, bf16 hi/lo
// ---------------------------------------------------------------------------
__global__ __launch_bounds__(256) void k_permW(const float* __restrict__ Wih0,
                                               unsigned short* __restrict__ Wfh,
                                               unsigned short* __restrict__ Wfl)
{
    int idx = blockIdx.x * 256 + threadIdx.x;     // < 30720
    int j = idx & 7, lane = (idx >> 3) & 63, nt = (idx >> 9) & 3, ch = idx >> 11;
    int g = nt * 16 + (lane & 15);
    int k = (lane >> 4) * 8 + j;
    int f = ch * 32 + k, q = f >> 4, h = f & 15;
    float v = Wih0[g * 480 + h * 30 + q];
    unsigned int uv = __float_as_uint(v);
    Wfh[idx] = (unsigned short)(uv >> 16);
    Wfl[idx] = f2bf_rne(v - __uint_as_float(uv & 0xFFFF0000u));
}

// ---------------------------------------------------------------------------
// Kernel 0b: generic fp32 -> bf16 hi/lo split (per float4)
// ---------------------------------------------------------------------------
__global__ __launch_bounds__(256) void k_cvt(const float* __restrict__ in,
                                             unsigned short* __restrict__ oh,
                                             unsigned short* __restrict__ ol,
                                             int n4)
{
    int i = blockIdx.x * 256 + threadIdx.x;
    if (i >= n4) return;
    float4 v = ((const float4*)in)[i];
    float vv[4] = {v.x, v.y, v.z, v.w};
    unsigned short hs[4], ls[4];
    #pragma unroll
    for (int e = 0; e < 4; ++e) {
        unsigned int u = __float_as_uint(vv[e]);
        hs[e] = (unsigned short)(u >> 16);
        ls[e] = f2bf_rne(vv[e] - __uint_as_float(u & 0xFFFF0000u));
    }
    uint2 ph = make_uint2((unsigned)hs[0] | ((unsigned)hs[1] << 16),
                          (unsigned)hs[2] | ((unsigned)hs[3] << 16));
    uint2 pl = make_uint2((unsigned)ls[0] | ((unsigned)ls[1] << 16),
                          (unsigned)ls[2] | ((unsigned)ls[3] << 16));
    *(uint2*)&oh[i * 4] = ph;
    *(uint2*)&ol[i * 4] = pl;
}

// ---------------------------------------------------------------------------
// Kernel 1: dual-axis attention + conv/bn/pool + MFMA GEMM. [round-12 verbatim]
// ---------------------------------------------------------------------------
__global__ __launch_bounds__(256, 4) void k_attn_conv(
    const float* __restrict__ x1, const float* __restrict__ x2,
    const float* __restrict__ w_x_q, const float* __restrict__ w_x_k,
    const float* __restrict__ w_y_q, const float* __restrict__ w_y_k,
    const float* __restrict__ pos_emb,
    const float* __restrict__ conv_w, const float* __restrict__ conv_b,
    const float* __restrict__ bn_g, const float* __restrict__ bn_b,
    const float* __restrict__ bn_m, const float* __restrict__ bn_v,
    const unsigned short* __restrict__ Wfh, const unsigned short* __restrict__ Wfl,
    float* __restrict__ pre0)
{
    __shared__ float xs[128 * LSX];
    __shared__ float xkp[2][64], ykv[128], uu[64], vv[128];
    __shared__ float sxs[128], sysp[2][64], sys[64];
    __shared__ float cw[16][4], cbs[16], bnsh[16];

    const int bg = blockIdx.x;
    const int t  = threadIdx.x;
    const float* x = (bg < 512 ? x1 : x2) + (size_t)(bg & 511) * 8192;

    #pragma unroll
    for (int r = 0; r < 32; ++r) {
        int pos = r * 256 + t;
        xs[(pos >> 6) * LSX + (pos & 63)] = x[pos];
    }
    if (t < 16) {
        float sc = bn_g[t] * rsqrtf(bn_v[t] + 1e-5f);   // > 0 for given inputs
        bnsh[t] = bn_b[t] - bn_m[t] * sc;
        cbs[t]  = conv_b[t] * sc;
        cw[t][0] = conv_w[t * 4 + 0] * sc; cw[t][1] = conv_w[t * 4 + 1] * sc;
        cw[t][2] = conv_w[t * 4 + 2] * sc; cw[t][3] = conv_w[t * 4 + 3] * sc;
    }
    __syncthreads();

    if (t < 128) {
        int n = t & 63, hf = t >> 6;
        const float* base = &xs[hf * 64 * LSX + n];
        const float* wk = w_x_k + hf * 64;
        float s0 = 0.f, s1 = 0.f, s2 = 0.f, s3 = 0.f;
        for (int l = 0; l < 64; l += 4) {
            s0 += base[(l + 0) * LSX] * wk[l + 0];
            s1 += base[(l + 1) * LSX] * wk[l + 1];
            s2 += base[(l + 2) * LSX] * wk[l + 2];
            s3 += base[(l + 3) * LSX] * wk[l + 3];
        }
        xkp[hf][n] = (s0 + s1) + (s2 + s3);
    } else {
        int l = t - 128;
        const float* row = &xs[l * LSX];
        float s0 = 0.f, s1 = 0.f, s2 = 0.f, s3 = 0.f;
        for (int n = 0; n < 64; n += 4) {
            s0 += w_y_k[n + 0] * row[n + 0];
            s1 += w_y_k[n + 1] * row[n + 1];
            s2 += w_y_k[n + 2] * row[n + 2];
            s3 += w_y_k[n + 3] * row[n + 3];
        }
        ykv[l] = (s0 + s1) + (s2 + s3);
    }
    __syncthreads();

    if (t < 64) {
        const float* wq = w_x_q + t * 64;
        float s0 = 0.f, s1 = 0.f, s2 = 0.f, s3 = 0.f;
        for (int n = 0; n < 64; n += 4) {
            s0 += wq[n + 0] * (xkp[0][n + 0] + xkp[1][n + 0]);
            s1 += wq[n + 1] * (xkp[0][n + 1] + xkp[1][n + 1]);
            s2 += wq[n + 2] * (xkp[0][n + 2] + xkp[1][n + 2]);
            s3 += wq[n + 3] * (xkp[0][n + 3] + xkp[1][n + 3]);
        }
        uu[t] = (s0 + s1) + (s2 + s3);
    } else if (t < 192) {
        int m = t - 64;
        float s0 = 0.f, s1 = 0.f, s2 = 0.f, s3 = 0.f;
        for (int l = 0; l < 128; l += 4) {
            s0 += ykv[l + 0] * w_y_q[(l + 0) * 128 + m];
            s1 += ykv[l + 1] * w_y_q[(l + 1) * 128 + m];
            s2 += ykv[l + 2] * w_y_q[(l + 2) * 128 + m];
            s3 += ykv[l + 3] * w_y_q[(l + 3) * 128 + m];
        }
        vv[m] = (s0 + s1) + (s2 + s3);
    }
    __syncthreads();

    if (t < 128) {
        const float* row = &xs[t * LSX];
        float s0 = 0.f, s1 = 0.f, s2 = 0.f, s3 = 0.f;
        for (int m = 0; m < 64; m += 4) {
            s0 += row[m + 0] * uu[m + 0];
            s1 += row[m + 1] * uu[m + 1];
            s2 += row[m + 2] * uu[m + 2];
            s3 += row[m + 3] * uu[m + 3];
        }
        sxs[t] = (s0 + s1) + (s2 + s3);
    } else {
        int n = (t - 128) & 63, hf = (t - 128) >> 6;
        const float* base = &xs[hf * 64 * LSX + n];
        const float* vp = vv + hf * 64;
        float s0 = 0.f, s1 = 0.f, s2 = 0.f, s3 = 0.f;
        for (int m = 0; m < 64; m += 4) {
            s0 += vp[m + 0] * base[(m + 0) * LSX];
            s1 += vp[m + 1] * base[(m + 1) * LSX];
            s2 += vp[m + 2] * base[(m + 2) * LSX];
            s3 += vp[m + 3] * base[(m + 3) * LSX];
        }
        sysp[hf][n] = (s0 + s1) + (s2 + s3);
    }
    __syncthreads();

    if (t < 64) {
        float a = sxs[t], b = sxs[t + 64];
        float mx = fmaxf(a, b);
        #pragma unroll
        for (int d = 32; d > 0; d >>= 1) mx = fmaxf(mx, __shfl_xor(mx, d, 64));
        float e0 = __expf(a - mx), e1 = __expf(b - mx);
        float s = e0 + e1;
        #pragma unroll
        for (int d = 32; d > 0; d >>= 1) s += __shfl_xor(s, d, 64);
        float r = 10.f / s;
        sxs[t] = e0 * r; sxs[t + 64] = e1 * r;
    } else if (t < 128) {
        int n = t - 64;
        float a = sysp[0][n] + sysp[1][n];
        float mx = a;
        #pragma unroll
        for (int d = 32; d > 0; d >>= 1) mx = fmaxf(mx, __shfl_xor(mx, d, 64));
        float e = __expf(a - mx);
        float s = e;
        #pragma unroll
        for (int d = 32; d > 0; d >>= 1) s += __shfl_xor(s, d, 64);
        sys[n] = e * (10.f / s);
    }
    __syncthreads();

    #pragma unroll
    for (int r = 0; r < 32; ++r) {
        int pos = r * 256 + t;
        int l = pos >> 6, n = pos & 63;
        xs[l * LSX + n] = xs[l * LSX + n] * sxs[l] * sys[n] + pos_emb[pos];
    }
    __syncthreads();

    const int lane = t & 63, w = t >> 6;
    const int m16 = lane & 15, kq = lane >> 4;
    const int hb = (kq & 1) * 8;
    const int qoff = kq >> 1;

    float cwr0[8], cwr1[8], cwr2[8], cwr3[8], cbr[8], bhr[8];
    #pragma unroll
    for (int j = 0; j < 8; ++j) {
        cwr0[j] = cw[hb + j][0]; cwr1[j] = cw[hb + j][1];
        cwr2[j] = cw[hb + j][2]; cwr3[j] = cw[hb + j][3];
        cbr[j] = cbs[hb + j]; bhr[j] = bnsh[hb + j];
    }

    f32x4 acc[2][4];
    #pragma unroll
    for (int mt = 0; mt < 2; ++mt)
        #pragma unroll
        for (int nt = 0; nt < 4; ++nt) {
            f32x4 z = {0.f, 0.f, 0.f, 0.f};
            acc[mt][nt] = z;
        }

    for (int ch = 0; ch < 15; ++ch) {
        bf16x8 ah[2], al[2];
        const int q2 = 2 * (2 * ch + qoff);
        #pragma unroll
        for (int mt = 0; mt < 2; ++mt) {
            int row = w * 32 + mt * 16 + m16;
            const float* xr = &xs[row * LSX + q2];
            float o0 = xr[0], o1 = xr[1], o2 = xr[2], o3 = xr[3], o4 = xr[4];
            union { unsigned short us[8]; bf16x8 bv; } vh, vl;
            #pragma unroll
            for (int j = 0; j < 8; ++j) {
                float a = fmaf(o0, cwr0[j], fmaf(o1, cwr1[j], fmaf(o2, cwr2[j], fmaf(o3, cwr3[j], cbr[j]))));
                float b = fmaf(o1, cwr0[j], fmaf(o2, cwr1[j], fmaf(o3, cwr2[j], fmaf(o4, cwr3[j], cbr[j]))));
                float v = fmaxf(fmaxf(a, 0.f), fmaxf(b, 0.f)) + bhr[j];
                unsigned int uv = __float_as_uint(v);
                vh.us[j] = (unsigned short)(uv >> 16);
                vl.us[j] = f2bf_rne(v - __uint_as_float(uv & 0xFFFF0000u));
            }
            ah[mt] = vh.bv; al[mt] = vl.bv;
        }
        #pragma unroll
        for (int nh = 0; nh < 2; ++nh) {
            bf16x8 bh[2], bl[2];
            #pragma unroll
            for (int ni = 0; ni < 2; ++ni) {
                int o = ((ch * 4 + nh * 2 + ni) * 64 + lane) * 8;
                bh[ni] = *(const bf16x8*)&Wfh[o];
                bl[ni] = *(const bf16x8*)&Wfl[o];
            }
            #pragma unroll
            for (int mt = 0; mt < 2; ++mt)
                #pragma unroll
                for (int ni = 0; ni < 2; ++ni) {
                    int nt = nh * 2 + ni;
                    acc[mt][nt] = __builtin_amdgcn_mfma_f32_16x16x32_bf16(ah[mt], bh[ni], acc[mt][nt], 0, 0, 0);
                    acc[mt][nt] = __builtin_amdgcn_mfma_f32_16x16x32_bf16(al[mt], bh[ni], acc[mt][nt], 0, 0, 0);
                    acc[mt][nt] = __builtin_amdgcn_mfma_f32_16x16x32_bf16(ah[mt], bl[ni], acc[mt][nt], 0, 0, 0);
                }
        }
    }

    #pragma unroll
    for (int mt = 0; mt < 2; ++mt)
        #pragma unroll
        for (int nt = 0; nt < 4; ++nt)
            #pragma unroll
            for (int r = 0; r < 4; ++r) {
                int row = w * 32 + mt * 16 + (lane >> 4) * 4 + r;
                int col = nt * 16 + m16;
                pre0[(size_t)bg * 8192 + row * 64 + col] = acc[mt][nt][r];
            }
}

// ---------------------------------------------------------------------------
// Kernel 2: producer-consumer 2-wave LSTM, barrier-paired double buffering,
// batch = 8 steps per barrier. One block per sequence. [round-12 verbatim,
// measured 109 µs — best of 8 structures tried]
// ---------------------------------------------------------------------------
__global__ __launch_bounds__(128) void k_lstm(
    const float* __restrict__ pre0,
    const float* __restrict__ Whh0,
    const float* __restrict__ Wih1, const float* __restrict__ Whh1,
    const float* __restrict__ bih0, const float* __restrict__ bhh0,
    const float* __restrict__ bih1, const float* __restrict__ bhh1,
    unsigned short* __restrict__ fbh, unsigned short* __restrict__ fbl)
{
    __shared__ float zbuf[2][8][64];

    const int blk = blockIdx.x;
    const int i = blk >> 7, j = blk & 127;
    const int tid = threadIdx.x;
    const int lane = tid & 63;
    const int wv = tid >> 6;
    const int a = lane & 3, u = lane >> 2;
    const int row = a * 16 + u;          // torch gate-row index
    const float pm = (a == 2) ? -2.f : -1.f;
    const float ka = (a == 2) ?  2.f :  1.f;
    const float kb = (a == 2) ? -1.f :  0.f;

    if (wv == 0) {
        float w0[16], wi1[16];
        #pragma unroll
        for (int m = 0; m < 16; ++m) {
            w0[m]  = Whh0[row * 16 + m];
            wi1[m] = Wih1[row * 16 + m];
        }
        const float b0 = bih0[row] + bhh0[row];
        float h0[16];
        #pragma unroll
        for (int m = 0; m < 16; ++m) h0[m] = 0.f;
        float c0 = 0.f;

        const float* pp = pre0 + (size_t)i * 4194304 + (size_t)j * 64 + row;
        float pf[8];
        #pragma unroll
        for (int d = 0; d < 8; ++d) pf[d] = pp[(size_t)d * 8192];

#define STEP0(PRE, DD, BB)                                                      \
    {                                                                           \
        float sA = 0.f, sB = 0.f, sC = 0.f, sD = 0.f;                           \
        _Pragma("unroll")                                                       \
        for (int m = 0; m < 4; ++m) {                                           \
            sA += h0[m]      * w0[m];                                           \
            sB += h0[m + 4]  * w0[m + 4];                                       \
            sC += h0[m + 8]  * w0[m + 8];                                       \
            sD += h0[m + 12] * w0[m + 12];                                      \
        }                                                                       \
        float g0 = (PRE) + b0 + ((sA + sB) + (sC + sD));                        \
        float e0 = __expf(pm * g0);                                             \
        float v0 = fmaf(__builtin_amdgcn_rcpf(1.f + e0), ka, kb);               \
        float si = QB(v0, 0x00), sf = QB(v0, 0x55);                             \
        float tg = QB(v0, 0xAA), so = QB(v0, 0xFF);                             \
        c0 = fmaf(sf, c0, si * tg);                                             \
        float ec = __expf(-2.f * c0);                                           \
        float h0n = so * fmaf(2.f, __builtin_amdgcn_rcpf(1.f + ec), -1.f);      \
        float hn[16];                                                           \
        _Pragma("unroll")                                                       \
        for (int m = 0; m < 16; ++m) hn[m] = RDLANE(h0n, 4 * m);                \
        float zA = 0.f, zB = 0.f, zC = 0.f, zD = 0.f;                           \
        _Pragma("unroll")                                                       \
        for (int m = 0; m < 4; ++m) {                                           \
            zA += hn[m]      * wi1[m];                                          \
            zB += hn[m + 4]  * wi1[m + 4];                                      \
            zC += hn[m + 8]  * wi1[m + 8];                                      \
            zD += hn[m + 12] * wi1[m + 12];                                     \
        }                                                                       \
        zbuf[BB][DD][lane] = (zA + zB) + (zC + zD);                             \
        _Pragma("unroll")                                                       \
        for (int m = 0; m < 16; ++m) h0[m] = hn[m];                             \
    }

        for (int tb = 0; tb < 64; ++tb) {
            const int bb = tb & 1;
            float nx[8];
            #pragma unroll
            for (int d = 0; d < 8; ++d)
                nx[d] = pp[(size_t)(tb * 8 + 8 + d) * 8192];
            STEP0(pf[0], 0, bb);
            STEP0(pf[1], 1, bb);
            STEP0(pf[2], 2, bb);
            STEP0(pf[3], 3, bb);
            STEP0(pf[4], 4, bb);
            STEP0(pf[5], 5, bb);
            STEP0(pf[6], 6, bb);
            STEP0(pf[7], 7, bb);
            #pragma unroll
            for (int d = 0; d < 8; ++d) pf[d] = nx[d];
            __syncthreads();
        }
        __syncthreads();   // pair with consumer's initial barrier
#undef STEP0
    } else {
        float wh1[16];
        #pragma unroll
        for (int m = 0; m < 16; ++m) wh1[m] = Whh1[row * 16 + m];
        const float b1 = bih1[row] + bhh1[row];
        float h1[16];
        #pragma unroll
        for (int m = 0; m < 16; ++m) h1[m] = 0.f;
        float c1 = 0.f;

        const size_t fbase = (size_t)i * 1048576 + (size_t)j * 16 + u;
        const bool st = (a == 0);

#define STEP1(ZZ, TT)                                                           \
    {                                                                           \
        float tA = 0.f, tB = 0.f, tC = 0.f, tD = 0.f;                           \
        _Pragma("unroll")                                                       \
        for (int m = 0; m < 4; ++m) {                                           \
            tA += h1[m]      * wh1[m];                                          \
            tB += h1[m + 4]  * wh1[m + 4];                                      \
            tC += h1[m + 8]  * wh1[m + 8];                                      \
            tD += h1[m + 12] * wh1[m + 12];                                     \
        }                                                                       \
        float g1 = (ZZ) + b1 + ((tA + tB) + (tC + tD));                         \
        float e1 = __expf(pm * g1);                                             \
        float v1 = fmaf(__builtin_amdgcn_rcpf(1.f + e1), ka, kb);               \
        float si1 = QB(v1, 0x00), sf1 = QB(v1, 0x55);                           \
        float tg1 = QB(v1, 0xAA), so1 = QB(v1, 0xFF);                           \
        c1 = fmaf(sf1, c1, si1 * tg1);                                          \
        float ec1 = __expf(-2.f * c1);                                          \
        float h1n = so1 * fmaf(2.f, __builtin_amdgcn_rcpf(1.f + ec1), -1.f);    \
        if (st) {                                                               \
            unsigned int uh = __float_as_uint(h1n);                             \
            fbh[fbase + (size_t)(TT) * 2048] = (unsigned short)(uh >> 16);      \
            fbl[fbase + (size_t)(TT) * 2048] =                                  \
                f2bf_rne(h1n - __uint_as_float(uh & 0xFFFF0000u));              \
        }                                                                       \
        _Pragma("unroll")                                                       \
        for (int m = 0; m < 16; ++m) h1[m] = RDLANE(h1n, 4 * m);                \
    }

        __syncthreads();   // wait for batch 0
        for (int tb = 0; tb < 64; ++tb) {
            const int bb = tb & 1;
            float zz[8];
            #pragma unroll
            for (int d = 0; d < 8; ++d) zz[d] = zbuf[bb][d][lane];
            const int t0 = tb * 8;
            STEP1(zz[0], t0 + 0);
            STEP1(zz[1], t0 + 1);
            STEP1(zz[2], t0 + 2);
            STEP1(zz[3], t0 + 3);
            STEP1(zz[4], t0 + 4);
            STEP1(zz[5], t0 + 5);
            STEP1(zz[6], t0 + 6);
            STEP1(zz[7], t0 + 7);
            __syncthreads();
        }
#undef STEP1
    }
}

// ---------------------------------------------------------------------------
// Kernel 3/4: MFMA bf16 GEMM on pre-split hi/lo inputs. 64x64 tile,
// grid 16x16 = 256 blocks, 4 waves = 4 quadrants.  [unchanged]
// ---------------------------------------------------------------------------
__global__ __launch_bounds__(256) void k_fcmm(
    const unsigned short* __restrict__ Ahg, const unsigned short* __restrict__ Alg,
    const unsigned short* __restrict__ Bhg, const unsigned short* __restrict__ Blg,
    const float* __restrict__ bias,
    float* __restrict__ Cf, unsigned short* __restrict__ Chh,
    unsigned short* __restrict__ Chl,
    int N, int K)
{
    __shared__ unsigned short Ah[64 * FCS], Al[64 * FCS];
    __shared__ unsigned short Bh[64 * FCS], Bl[64 * FCS];
    const int t = threadIdx.x;
    const int lane = t & 63, w = t >> 6;
    const int wr = (w >> 1) * 32, wc = (w & 1) * 32;
    const int m0 = blockIdx.y * 64, n0 = blockIdx.x * 64;
    const int m16 = lane & 15, kb = (lane >> 4) * 8;
    const int sr = t >> 2, skg = (t & 3) * 8;

    f32x4 acc[2][2];
    #pragma unroll
    for (int mt = 0; mt < 2; ++mt)
        #pragma unroll
        for (int nt = 0; nt < 2; ++nt) {
            f32x4 z = {0.f, 0.f, 0.f, 0.f};
            acc[mt][nt] = z;
        }

    for (int kc = 0; kc < K; kc += 32) {
        size_t ga = (size_t)(m0 + sr) * K + kc + skg;
        size_t gb = (size_t)(n0 + sr) * K + kc + skg;
        *(uint4*)&Ah[sr * FCS + skg] = *(const uint4*)&Ahg[ga];
        *(uint4*)&Al[sr * FCS + skg] = *(const uint4*)&Alg[ga];
        *(uint4*)&Bh[sr * FCS + skg] = *(const uint4*)&Bhg[gb];
        *(uint4*)&Bl[sr * FCS + skg] = *(const uint4*)&Blg[gb];
        __syncthreads();

        bf16x8 afh[2], afl[2], bfh[2], bfl[2];
        #pragma unroll
        for (int mt = 0; mt < 2; ++mt) {
            int off = (wr + mt * 16 + m16) * FCS + kb;
            afh[mt] = *(const bf16x8*)&Ah[off];
            afl[mt] = *(const bf16x8*)&Al[off];
        }
        #pragma unroll
        for (int nt = 0; nt < 2; ++nt) {
            int off = (wc + nt * 16 + m16) * FCS + kb;
            bfh[nt] = *(const bf16x8*)&Bh[off];
            bfl[nt] = *(const bf16x8*)&Bl[off];
        }
        #pragma unroll
        for (int mt = 0; mt < 2; ++mt)
            #pragma unroll
            for (int nt = 0; nt < 2; ++nt) {
                acc[mt][nt] = __builtin_amdgcn_mfma_f32_16x16x32_bf16(afh[mt], bfh[nt], acc[mt][nt], 0, 0, 0);
                acc[mt][nt] = __builtin_amdgcn_mfma_f32_16x16x32_bf16(afl[mt], bfh[nt], acc[mt][nt], 0, 0, 0);
                acc[mt][nt] = __builtin_amdgcn_mfma_f32_16x16x32_bf16(afh[mt], bfl[nt], acc[mt][nt], 0, 0, 0);
            }
        __syncthreads();
    }

    #pragma unroll
    for (int mt = 0; mt < 2; ++mt)
        #pragma unroll
        for (int nt = 0; nt < 2; ++nt)
            #pragma unroll
            for (int r = 0; r < 4; ++r) {
                int rr = m0 + wr + mt * 16 + (lane >> 4) * 4 + r;
                int cc = n0 + wc + nt * 16 + m16;
                float v = acc[mt][nt][r] + bias[cc];
                v = (v > 0.f) ? v : 0.01f * v;
                if (Cf) {
                    Cf[(size_t)rr * N + cc] = v;
                } else {
                    unsigned int uv = __float_as_uint(v);
                    Chh[(size_t)rr * N + cc] = (unsigned short)(uv >> 16);
                    Chl[(size_t)rr * N + cc] =
                        f2bf_rne(v - __uint_as_float(uv & 0xFFFF0000u));
                }
            }
}

// ---------------------------------------------------------------------------
// Kernel 5: FC3 [1024,1024] @ [20,1024]^T + bias -> d_out [1024,20]
// ---------------------------------------------------------------------------
__global__ __launch_bounds__(256) void k_fc3(
    const float* __restrict__ A, const float* __restrict__ W,
    const float* __restrict__ bias, float* __restrict__ out)
{
    __shared__ float row[1024];
    __shared__ float red[20][8];
    const int m = blockIdx.x;
    const int t = threadIdx.x;
    #pragma unroll
    for (int r = 0; r < 4; ++r) row[r * 256 + t] = A[(size_t)m * 1024 + r * 256 + t];
    __syncthreads();
    if (t < 160) {
        int o = t >> 3, seg = t & 7;
        const float* w = W + (size_t)o * 1024 + seg * 128;
        const float* rr = &row[seg * 128];
        float s = 0.f;
        for (int kk = 0; kk < 128; ++kk) s += rr[kk] * w[kk];
        red[o][seg] = s;
    }
    __syncthreads();
    if (t < 20) {
        float s = bias[t];
        #pragma unroll
        for (int seg = 0; seg < 8; ++seg) s += red[t][seg];
        out[(size_t)m * 20 + t] = s;
    }
}

// ---------------------------------------------------------------------------
extern "C" void kernel_launch(void* const* d_in, const int* in_sizes, int n_in,
                              void* d_out, int out_size, void* d_ws, size_t ws_size,
                              hipStream_t stream) {
    const float* in1    = (const float*)d_in[0];
    const float* in2    = (const float*)d_in[1];
    const float* w_x_q  = (const float*)d_in[2];
    const float* w_x_k  = (const float*)d_in[3];
    const float* w_y_q  = (const float*)d_in[4];
    const float* w_y_k  = (const float*)d_in[5];
    const float* posemb = (const float*)d_in[6];
    const float* conv_w = (const float*)d_in[7];
    const float* conv_b = (const float*)d_in[8];
    const float* bn_g   = (const float*)d_in[9];
    const float* bn_b   = (const float*)d_in[10];
    const float* bn_m   = (const float*)d_in[11];
    const float* bn_v   = (const float*)d_in[12];
    const float* Wih0   = (const float*)d_in[13];
    const float* Whh0   = (const float*)d_in[14];
    const float* bih0   = (const float*)d_in[15];
    const float* bhh0   = (const float*)d_in[16];
    const float* Wih1   = (const float*)d_in[17];
    const float* Whh1   = (const float*)d_in[18];
    const float* bih1   = (const float*)d_in[19];
    const float* bhh1   = (const float*)d_in[20];
    const float* fc1w   = (const float*)d_in[21];
    const float* fc1b   = (const float*)d_in[22];
    const float* fc2w   = (const float*)d_in[23];
    const float* fc2b   = (const float*)d_in[24];
    const float* fc3w   = (const float*)d_in[25];
    const float* fc3b   = (const float*)d_in[26];
    float* out = (float*)d_out;

    float* ws = (float*)d_ws;
    float* pre0            = ws;                               // 8,466,432
    unsigned short* fbh    = (unsigned short*)(ws + 8466432);  // 2,097,152 us
    unsigned short* fbl    = (unsigned short*)(ws + 9515008);
    unsigned short* f1h    = (unsigned short*)(ws + 10563584); // 1,048,576 us
    unsigned short* f1l    = (unsigned short*)(ws + 11087872);
    float* f2              = ws + 11612160;                    // 1,048,576 f
    unsigned short* w1h    = (unsigned short*)(ws + 12660736); // 2,097,152 us
    unsigned short* w1l    = (unsigned short*)(ws + 13709312);
    unsigned short* w2h    = (unsigned short*)(ws + 14757888); // 1,048,576 us
    unsigned short* w2l    = (unsigned short*)(ws + 15282176);
    unsigned short* Wfh    = (unsigned short*)(ws + 15806464); // 30,720 us
    unsigned short* Wfl    = (unsigned short*)(ws + 15821824);

    k_permW<<<120, 256, 0, stream>>>(Wih0, Wfh, Wfl);
    k_cvt<<<2048, 256, 0, stream>>>(fc1w, w1h, w1l, 524288);
    k_cvt<<<1024, 256, 0, stream>>>(fc2w, w2h, w2l, 262144);
    k_attn_conv<<<1024, 256, 0, stream>>>(in1, in2, w_x_q, w_x_k, w_y_q, w_y_k,
                                          posemb, conv_w, conv_b, bn_g, bn_b,
                                          bn_m, bn_v, Wfh, Wfl, pre0);
    k_lstm<<<256, 128, 0, stream>>>(pre0, Whh0, Wih1, Whh1,
                                    bih0, bhh0, bih1, bhh1, fbh, fbl);
    dim3 gfc(16, 16);
    k_fcmm<<<gfc, 256, 0, stream>>>(fbh, fbl, w1h, w1l, fc1b,
                                    nullptr, f1h, f1l, 1024, 2048);
    k_fcmm<<<gfc, 256, 0, stream>>>(f1h, f1l, w2h, w2l, fc2b,
                                    f2, nullptr, nullptr, 1024, 1024);
    k_fc3<<<1024, 256, 0, stream>>>(f2, fc3w, fc3b, out);
}